// Round 8
// baseline (66.346 us; speedup 1.0000x reference)
//
#include <hip/hip_runtime.h>
#include <hip/hip_bf16.h>

typedef __attribute__((ext_vector_type(8))) short bf16x8;
typedef __attribute__((ext_vector_type(4))) float f32x4;
typedef unsigned short u16;

static __device__ __forceinline__ u16 f2bf(float f) {
  unsigned u = __builtin_bit_cast(unsigned, f);
  return (u16)((u + 0x7fffu + ((u >> 16) & 1u)) >> 16);
}

// ================= K1: weights -> Apre (256x1024 bf16), Bmat (1024x256 bf16) ==========
// (round-3/7 proven body, unchanged)
__global__ __launch_bounds__(256) void trl_w(
    const float* __restrict__ W0, const float* __restrict__ W1,
    const float* __restrict__ W2, const float* __restrict__ W3,
    const float* __restrict__ W4, const float* __restrict__ W5,
    const float* __restrict__ W6, const float* __restrict__ W7,
    u16* __restrict__ Apre, u16* __restrict__ Bmat) {
  __shared__ float S1[512];
  __shared__ float S2[4096];
  const int tid = threadIdx.x;
  const int b = blockIdx.x;
  if (b < 64) {
    const int r1 = b >> 2;
    const int j3base = (b & 3) << 2;
#pragma unroll
    for (int e0 = 0; e0 < 512; e0 += 256) {
      const int e = e0 + tid;
      const int i0 = e & 3, i1 = (e >> 2) & 7, j1 = e >> 5;
      float s = 0.f;
#pragma unroll
      for (int r0 = 0; r0 < 16; ++r0)
        s += W1[j1 * 128 + i1 * 16 + r0] * W0[(r0 * 16 + r1) * 4 + i0];
      S1[e] = s;  // [j1*32 + i1*4 + i0]
    }
#pragma unroll
    for (int e0 = 0; e0 < 2048; e0 += 256) {
      const int e = e0 + tid;
      const int i3 = e & 3, pd = (e >> 2) & 3, j1 = (e >> 4) & 15, i2 = e >> 8;
      float s = 0.f;
#pragma unroll
      for (int j2 = 0; j2 < 16; ++j2)
        s += W3[(j3base + pd) * 64 + i3 * 16 + j2] * W2[j2 * 128 + i2 * 16 + j1];
      S2[e] = s;  // [i2*256 + j1*16 + pd*4 + i3]
    }
    __syncthreads();
    const int i0 = tid & 3, i1 = (tid >> 2) & 7, i2 = tid >> 5;
#pragma unroll
    for (int pd = 0; pd < 4; ++pd) {
      float a0 = 0.f, a1 = 0.f, a2 = 0.f, a3 = 0.f;
#pragma unroll
      for (int j1 = 0; j1 < 16; ++j1) {
        const float t = S1[j1 * 32 + i1 * 4 + i0];
        const float4 v = *(const float4*)&S2[i2 * 256 + j1 * 16 + pd * 4];
        a0 += t * v.x; a1 += t * v.y; a2 += t * v.z; a3 += t * v.w;
      }
      ushort4 o4;
      o4.x = f2bf(a0); o4.y = f2bf(a1); o4.z = f2bf(a2); o4.w = f2bf(a3);
      *(ushort4*)&Apre[(size_t)(4 * b + pd) * 1024 + i0 * 256 + i1 * 32 + i2 * 4] = o4;
    }
  } else {
    const int c = b - 64;
    const int kh = c >> 4, j5h = (c >> 1) & 7, j6hbase = (c & 1) << 2;
    {
      const int j5l = tid >> 4, j3 = tid & 15;
      float s = 0.f;
#pragma unroll
      for (int kl = 0; kl < 16; ++kl)
        s += W5[(j5h * 16 + j5l) * 16 + kl] * W4[(kh * 16 + kl) * 16 + j3];
      S1[tid] = s;  // [j5l*16 + j3]
    }
#pragma unroll
    for (int e0 = 0; e0 < 4096; e0 += 256) {
      const int e = e0 + tid;
      const int j5l = e & 15, j6hd = (e >> 4) & 3, r1 = (e >> 6) & 15, m7 = e >> 10;
      float s = 0.f;
#pragma unroll
      for (int d = 0; d < 16; ++d)
        s += W7[m7 * 256 + r1 * 16 + d] * W6[((j6hbase + j6hd) * 16 + d) * 16 + j5l];
      S2[e] = s;  // [((m7*16+r1)*4 + j6hd)*16 + j5l]
    }
    __syncthreads();
    const int r1 = (tid >> 2) & 15, j3q = tid & 3;
#pragma unroll
    for (int qq = 0; qq < 4; ++qq) {
      const int od = qq * 4 + (tid >> 6);
      const int m7 = od & 3, j6hd = od >> 2;
      float a0 = 0.f, a1 = 0.f, a2 = 0.f, a3 = 0.f;
#pragma unroll
      for (int j5l = 0; j5l < 16; ++j5l) {
        const float w = S2[((m7 * 16 + r1) * 4 + j6hd) * 16 + j5l];
        const float4 u = *(const float4*)&S1[j5l * 16 + j3q * 4];
        a0 += w * u.x; a1 += w * u.y; a2 += w * u.z; a3 += w * u.w;
      }
      ushort4 o4;
      o4.x = f2bf(a0); o4.y = f2bf(a1); o4.z = f2bf(a2); o4.w = f2bf(a3);
      *(ushort4*)&Bmat[(size_t)(16 * c + od) * 256 + r1 * 16 + j3q * 4] = o4;
    }
  }
}

// ============ K2: fused per-m-slab GEMM, 256 blocks (32 m-slabs x 8 n-eighths) =========
// p: m-slab = p&31 (same-slab blocks land on same XCD: p%8 = slab%8), q = p>>5.
// Phase 1: full Cb slab (32x256) = bf16(x slab) @ Apre^T, K=1024 sequential per wave
//          (wave covers 64 Cb cols) -> XOR-swizzled LDS (round-2-proven scheme).
// Phase 2: out slab cols [q*128, q*128+128) = Cbs @ Bmat^T + bias (wave covers 32 cols).
__global__ __launch_bounds__(256) void trl_f(const float* __restrict__ x,
                                             const u16* __restrict__ Apre,
                                             const u16* __restrict__ Bmat,
                                             const float* __restrict__ bias,
                                             float* __restrict__ out) {
  __shared__ u16 Cbs[32 * 256];  // addr(row,col) = row*256 + (((col>>3)^(row&7))<<3 | (col&7))
  const int tid = threadIdx.x;
  const int wave = tid >> 6, lane = tid & 63;
  const int l15 = lane & 15, l4 = lane >> 4;
  const int p = blockIdx.x;
  const int m0 = (p & 31) * 32;
  const int q = p >> 5;

  // ---- phase 1 ----
  f32x4 acc1[2][4] = {};
  const float* xr0 = x + (size_t)(m0 + l15) * 1024;
  const float* xr1 = x + (size_t)(m0 + 16 + l15) * 1024;
#pragma unroll 4
  for (int ks = 0; ks < 32; ++ks) {
    const int k = ks * 32 + l4 * 8;
    const float4 f0 = *(const float4*)&xr0[k];
    const float4 f1 = *(const float4*)&xr0[k + 4];
    const float4 g0 = *(const float4*)&xr1[k];
    const float4 g1 = *(const float4*)&xr1[k + 4];
    bf16x8 a0, a1;
    a0[0] = (short)f2bf(f0.x); a0[1] = (short)f2bf(f0.y);
    a0[2] = (short)f2bf(f0.z); a0[3] = (short)f2bf(f0.w);
    a0[4] = (short)f2bf(f1.x); a0[5] = (short)f2bf(f1.y);
    a0[6] = (short)f2bf(f1.z); a0[7] = (short)f2bf(f1.w);
    a1[0] = (short)f2bf(g0.x); a1[1] = (short)f2bf(g0.y);
    a1[2] = (short)f2bf(g0.z); a1[3] = (short)f2bf(g0.w);
    a1[4] = (short)f2bf(g1.x); a1[5] = (short)f2bf(g1.y);
    a1[6] = (short)f2bf(g1.z); a1[7] = (short)f2bf(g1.w);
#pragma unroll
    for (int nt = 0; nt < 4; ++nt) {
      const bf16x8 b0 = *(const bf16x8*)&Apre[(size_t)(wave * 64 + nt * 16 + l15) * 1024 + k];
      acc1[0][nt] = __builtin_amdgcn_mfma_f32_16x16x32_bf16(a0, b0, acc1[0][nt], 0, 0, 0);
      acc1[1][nt] = __builtin_amdgcn_mfma_f32_16x16x32_bf16(a1, b0, acc1[1][nt], 0, 0, 0);
    }
  }
#pragma unroll
  for (int fm = 0; fm < 2; ++fm)
#pragma unroll
    for (int nt = 0; nt < 4; ++nt) {
      const int col = wave * 64 + nt * 16 + l15;
#pragma unroll
      for (int r = 0; r < 4; ++r) {
        const int row = fm * 16 + l4 * 4 + r;
        Cbs[row * 256 + ((((col >> 3) ^ (row & 7)) << 3) | (col & 7))] = f2bf(acc1[fm][nt][r]);
      }
    }
  __syncthreads();

  // ---- phase 2 ----
  f32x4 acc2[2][2] = {};
#pragma unroll
  for (int kb = 0; kb < 8; ++kb) {
    const int g = kb * 4 + l4;
    const bf16x8 af0 = *(const bf16x8*)&Cbs[l15 * 256 + ((g ^ (l15 & 7)) << 3)];
    const bf16x8 af1 = *(const bf16x8*)&Cbs[(16 + l15) * 256 + ((g ^ (l15 & 7)) << 3)];
    const int k = kb * 32 + l4 * 8;
    const bf16x8 b0 = *(const bf16x8*)&Bmat[(size_t)(q * 128 + wave * 32 + l15) * 256 + k];
    const bf16x8 b1 = *(const bf16x8*)&Bmat[(size_t)(q * 128 + wave * 32 + 16 + l15) * 256 + k];
    acc2[0][0] = __builtin_amdgcn_mfma_f32_16x16x32_bf16(af0, b0, acc2[0][0], 0, 0, 0);
    acc2[0][1] = __builtin_amdgcn_mfma_f32_16x16x32_bf16(af0, b1, acc2[0][1], 0, 0, 0);
    acc2[1][0] = __builtin_amdgcn_mfma_f32_16x16x32_bf16(af1, b0, acc2[1][0], 0, 0, 0);
    acc2[1][1] = __builtin_amdgcn_mfma_f32_16x16x32_bf16(af1, b1, acc2[1][1], 0, 0, 0);
  }
#pragma unroll
  for (int fn = 0; fn < 2; ++fn) {
    const int gc = q * 128 + wave * 32 + fn * 16 + l15;
    const float bv = bias[gc];
#pragma unroll
    for (int fm = 0; fm < 2; ++fm)
#pragma unroll
      for (int r = 0; r < 4; ++r) {
        const int gr = m0 + fm * 16 + l4 * 4 + r;
        out[(size_t)gr * 1024 + gc] = acc2[fm][fn][r] + bv;
      }
  }
}

extern "C" void kernel_launch(void* const* d_in, const int* in_sizes, int n_in,
                              void* d_out, int out_size, void* d_ws, size_t ws_size,
                              hipStream_t stream) {
  const float* x  = (const float*)d_in[0];
  const float* W0 = (const float*)d_in[1];
  const float* W1 = (const float*)d_in[2];
  const float* W2 = (const float*)d_in[3];
  const float* W3 = (const float*)d_in[4];
  const float* W4 = (const float*)d_in[5];
  const float* W5 = (const float*)d_in[6];
  const float* W6 = (const float*)d_in[7];
  const float* W7 = (const float*)d_in[8];
  const float* bias = (const float*)d_in[9];

  char* ws = (char*)d_ws;
  u16* Apre = (u16*)(ws);                   // 512 KB (256x1024 bf16)
  u16* Bmat = (u16*)(ws + (512 << 10));     // 512 KB (1024x256 bf16)
  float* outp = (float*)d_out;

  trl_w<<<128, 256, 0, stream>>>(W0, W1, W2, W3, W4, W5, W6, W7, Apre, Bmat);
  trl_f<<<256, 256, 0, stream>>>(x, Apre, Bmat, bias, outp);
}

// Round 9
// 32.925 us; speedup vs baseline: 2.0150x; 2.0150x over previous
//
#include <hip/hip_runtime.h>
#include <hip/hip_bf16.h>

typedef __attribute__((ext_vector_type(8))) short bf16x8;
typedef __attribute__((ext_vector_type(4))) float f32x4;
typedef unsigned short u16;

static __device__ __forceinline__ u16 f2bf(float f) {
  unsigned u = __builtin_bit_cast(unsigned, f);
  return (u16)((u + 0x7fffu + ((u >> 16) & 1u)) >> 16);
}

// ================= K1: weights -> Apre/Bmat, x -> bf16 ==========
// Blocks 0..63 (type A): block b owns Apre rows p = 4b..4b+3
// Blocks 64..127 (type B): c = b-64 owns Bmat rows o = 16c..16c+15
// Blocks 128..191: xb = bf16(x) (coalesced float4)   [round-4 proven body]
__global__ __launch_bounds__(256) void trl_w(
    const float* __restrict__ W0, const float* __restrict__ W1,
    const float* __restrict__ W2, const float* __restrict__ W3,
    const float* __restrict__ W4, const float* __restrict__ W5,
    const float* __restrict__ W6, const float* __restrict__ W7,
    const float* __restrict__ x,
    u16* __restrict__ Apre, u16* __restrict__ Bmat, u16* __restrict__ xb) {
  __shared__ float S1[512];
  __shared__ float S2[4096];
  const int tid = threadIdx.x;
  const int b = blockIdx.x;
  if (b >= 128) {
    const int base4 = (b - 128) * 256 + tid;
#pragma unroll
    for (int q = 0; q < 16; ++q) {
      const int c = base4 + 16384 * q;
      const float4 v = reinterpret_cast<const float4*>(x)[c];
      ushort4 o4;
      o4.x = f2bf(v.x); o4.y = f2bf(v.y); o4.z = f2bf(v.z); o4.w = f2bf(v.w);
      reinterpret_cast<ushort4*>(xb)[c] = o4;
    }
    return;
  }
  if (b < 64) {
    const int r1 = b >> 2;
    const int j3base = (b & 3) << 2;
#pragma unroll
    for (int e0 = 0; e0 < 512; e0 += 256) {
      const int e = e0 + tid;
      const int i0 = e & 3, i1 = (e >> 2) & 7, j1 = e >> 5;
      float s = 0.f;
#pragma unroll
      for (int r0 = 0; r0 < 16; ++r0)
        s += W1[j1 * 128 + i1 * 16 + r0] * W0[(r0 * 16 + r1) * 4 + i0];
      S1[e] = s;  // [j1*32 + i1*4 + i0]
    }
#pragma unroll
    for (int e0 = 0; e0 < 2048; e0 += 256) {
      const int e = e0 + tid;
      const int i3 = e & 3, pd = (e >> 2) & 3, j1 = (e >> 4) & 15, i2 = e >> 8;
      float s = 0.f;
#pragma unroll
      for (int j2 = 0; j2 < 16; ++j2)
        s += W3[(j3base + pd) * 64 + i3 * 16 + j2] * W2[j2 * 128 + i2 * 16 + j1];
      S2[e] = s;  // [i2*256 + j1*16 + pd*4 + i3]
    }
    __syncthreads();
    const int i0 = tid & 3, i1 = (tid >> 2) & 7, i2 = tid >> 5;
#pragma unroll
    for (int pd = 0; pd < 4; ++pd) {
      float a0 = 0.f, a1 = 0.f, a2 = 0.f, a3 = 0.f;
#pragma unroll
      for (int j1 = 0; j1 < 16; ++j1) {
        const float t = S1[j1 * 32 + i1 * 4 + i0];
        const float4 v = *(const float4*)&S2[i2 * 256 + j1 * 16 + pd * 4];
        a0 += t * v.x; a1 += t * v.y; a2 += t * v.z; a3 += t * v.w;
      }
      ushort4 o4;
      o4.x = f2bf(a0); o4.y = f2bf(a1); o4.z = f2bf(a2); o4.w = f2bf(a3);
      *(ushort4*)&Apre[(size_t)(4 * b + pd) * 1024 + i0 * 256 + i1 * 32 + i2 * 4] = o4;
    }
  } else {
    const int c = b - 64;
    const int kh = c >> 4, j5h = (c >> 1) & 7, j6hbase = (c & 1) << 2;
    {
      const int j5l = tid >> 4, j3 = tid & 15;
      float s = 0.f;
#pragma unroll
      for (int kl = 0; kl < 16; ++kl)
        s += W5[(j5h * 16 + j5l) * 16 + kl] * W4[(kh * 16 + kl) * 16 + j3];
      S1[tid] = s;  // [j5l*16 + j3]
    }
#pragma unroll
    for (int e0 = 0; e0 < 4096; e0 += 256) {
      const int e = e0 + tid;
      const int j5l = e & 15, j6hd = (e >> 4) & 3, r1 = (e >> 6) & 15, m7 = e >> 10;
      float s = 0.f;
#pragma unroll
      for (int d = 0; d < 16; ++d)
        s += W7[m7 * 256 + r1 * 16 + d] * W6[((j6hbase + j6hd) * 16 + d) * 16 + j5l];
      S2[e] = s;  // [((m7*16+r1)*4 + j6hd)*16 + j5l]
    }
    __syncthreads();
    const int r1 = (tid >> 2) & 15, j3q = tid & 3;
#pragma unroll
    for (int qq = 0; qq < 4; ++qq) {
      const int od = qq * 4 + (tid >> 6);
      const int m7 = od & 3, j6hd = od >> 2;
      float a0 = 0.f, a1 = 0.f, a2 = 0.f, a3 = 0.f;
#pragma unroll
      for (int j5l = 0; j5l < 16; ++j5l) {
        const float w = S2[((m7 * 16 + r1) * 4 + j6hd) * 16 + j5l];
        const float4 u = *(const float4*)&S1[j5l * 16 + j3q * 4];
        a0 += w * u.x; a1 += w * u.y; a2 += w * u.z; a3 += w * u.w;
      }
      ushort4 o4;
      o4.x = f2bf(a0); o4.y = f2bf(a1); o4.z = f2bf(a2); o4.w = f2bf(a3);
      *(ushort4*)&Bmat[(size_t)(16 * c + od) * 256 + r1 * 16 + j3q * 4] = o4;
    }
  }
}

// ============ K2: Cb(1024x256 bf16) = xb @ Apre^T (round-2 proven body) ===============
// 256 blocks XCD-swizzled: m-slab = p&31, n-chunk = p>>5 -> the 8 blocks sharing an
// xb m-slab have p%8 == slab%8 -> same XCD. 4 waves split K=1024, LDS reduce.
__global__ __launch_bounds__(256) void trl_g1(const u16* __restrict__ xb,
                                              const u16* __restrict__ Apre,
                                              u16* __restrict__ Cb) {
  __shared__ float red[3][32 * 33];
  const int tid = threadIdx.x;
  const int wave = tid >> 6, lane = tid & 63;
  const int l15 = lane & 15, l4 = lane >> 4;
  const int p = blockIdx.x;
  const int m0 = (p & 31) * 32, n0 = (p >> 5) * 32;
  const int kbase = wave * 256;

  f32x4 acc[2][2] = {};
#pragma unroll
  for (int ks = 0; ks < 8; ++ks) {
    const int k = kbase + ks * 32 + l4 * 8;
    const bf16x8 a0 = *(const bf16x8*)&xb[(size_t)(m0 + l15) * 1024 + k];
    const bf16x8 a1 = *(const bf16x8*)&xb[(size_t)(m0 + 16 + l15) * 1024 + k];
    const bf16x8 b0 = *(const bf16x8*)&Apre[(size_t)(n0 + l15) * 1024 + k];
    const bf16x8 b1 = *(const bf16x8*)&Apre[(size_t)(n0 + 16 + l15) * 1024 + k];
    acc[0][0] = __builtin_amdgcn_mfma_f32_16x16x32_bf16(a0, b0, acc[0][0], 0, 0, 0);
    acc[0][1] = __builtin_amdgcn_mfma_f32_16x16x32_bf16(a0, b1, acc[0][1], 0, 0, 0);
    acc[1][0] = __builtin_amdgcn_mfma_f32_16x16x32_bf16(a1, b0, acc[1][0], 0, 0, 0);
    acc[1][1] = __builtin_amdgcn_mfma_f32_16x16x32_bf16(a1, b1, acc[1][1], 0, 0, 0);
  }
  if (wave > 0) {
#pragma unroll
    for (int fm = 0; fm < 2; ++fm)
#pragma unroll
      for (int fn = 0; fn < 2; ++fn)
#pragma unroll
        for (int r = 0; r < 4; ++r)
          red[wave - 1][(fm * 16 + l4 * 4 + r) * 33 + fn * 16 + l15] = acc[fm][fn][r];
  }
  __syncthreads();
  if (wave == 0) {
#pragma unroll
    for (int fm = 0; fm < 2; ++fm)
#pragma unroll
      for (int fn = 0; fn < 2; ++fn)
#pragma unroll
        for (int r = 0; r < 4; ++r) {
          const int row = fm * 16 + l4 * 4 + r, col = fn * 16 + l15;
          float s = acc[fm][fn][r] + red[0][row * 33 + col] + red[1][row * 33 + col] +
                    red[2][row * 33 + col];
          Cb[(size_t)(m0 + row) * 256 + n0 + col] = f2bf(s);
        }
  }
}

// ============ K3: out(1024x1024 f32) = Cb @ Bmat^T + bias (round-2 proven body) =======
// 256 blocks x 4 waves, each wave one 32x32 tile; XCD swizzle keeps Cb m-slab mates
// on one XCD (p = q+32j -> m-slab = p&31).
__global__ __launch_bounds__(256) void trl_g2(const u16* __restrict__ Cb,
                                              const u16* __restrict__ Bmat,
                                              const float* __restrict__ bias,
                                              float* __restrict__ out) {
  const int tid = threadIdx.x;
  const int wave = tid >> 6, lane = tid & 63;
  const int l15 = lane & 15, l4 = lane >> 4;
  const int p = blockIdx.x;
  const int b = (p & 31) * 8 + (p >> 5);
  const int tile = b * 4 + wave;
  const int m0 = (tile >> 5) * 32, n0 = (tile & 31) * 32;

  f32x4 acc[2][2] = {};
#pragma unroll
  for (int ks = 0; ks < 8; ++ks) {
    const int k = ks * 32 + l4 * 8;
    const bf16x8 a0 = *(const bf16x8*)&Cb[(size_t)(m0 + l15) * 256 + k];
    const bf16x8 a1 = *(const bf16x8*)&Cb[(size_t)(m0 + 16 + l15) * 256 + k];
    const bf16x8 b0 = *(const bf16x8*)&Bmat[(size_t)(n0 + l15) * 256 + k];
    const bf16x8 b1 = *(const bf16x8*)&Bmat[(size_t)(n0 + 16 + l15) * 256 + k];
    acc[0][0] = __builtin_amdgcn_mfma_f32_16x16x32_bf16(a0, b0, acc[0][0], 0, 0, 0);
    acc[0][1] = __builtin_amdgcn_mfma_f32_16x16x32_bf16(a0, b1, acc[0][1], 0, 0, 0);
    acc[1][0] = __builtin_amdgcn_mfma_f32_16x16x32_bf16(a1, b0, acc[1][0], 0, 0, 0);
    acc[1][1] = __builtin_amdgcn_mfma_f32_16x16x32_bf16(a1, b1, acc[1][1], 0, 0, 0);
  }
#pragma unroll
  for (int fn = 0; fn < 2; ++fn) {
    const int gc = n0 + fn * 16 + l15;
    const float bv = bias[gc];
#pragma unroll
    for (int fm = 0; fm < 2; ++fm)
#pragma unroll
      for (int r = 0; r < 4; ++r) {
        const int gr = m0 + fm * 16 + l4 * 4 + r;
        out[(size_t)gr * 1024 + gc] = acc[fm][fn][r] + bv;
      }
  }
}

extern "C" void kernel_launch(void* const* d_in, const int* in_sizes, int n_in,
                              void* d_out, int out_size, void* d_ws, size_t ws_size,
                              hipStream_t stream) {
  const float* x  = (const float*)d_in[0];
  const float* W0 = (const float*)d_in[1];
  const float* W1 = (const float*)d_in[2];
  const float* W2 = (const float*)d_in[3];
  const float* W3 = (const float*)d_in[4];
  const float* W4 = (const float*)d_in[5];
  const float* W5 = (const float*)d_in[6];
  const float* W6 = (const float*)d_in[7];
  const float* W7 = (const float*)d_in[8];
  const float* bias = (const float*)d_in[9];

  char* ws = (char*)d_ws;
  u16* Apre = (u16*)(ws);                   // 512 KB (256x1024 bf16)
  u16* Bmat = (u16*)(ws + (512 << 10));     // 512 KB (1024x256 bf16)
  u16* xb   = (u16*)(ws + (1024 << 10));    // 2 MB   (1024x1024 bf16)
  u16* Cb   = (u16*)(ws + (3072 << 10));    // 512 KB (1024x256 bf16)
  float* outp = (float*)d_out;

  trl_w<<<192, 256, 0, stream>>>(W0, W1, W2, W3, W4, W5, W6, W7, x, Apre, Bmat, xb);
  trl_g1<<<256, 256, 0, stream>>>(xb, Apre, Cb);
  trl_g2<<<256, 256, 0, stream>>>(Cb, Bmat, bias, outp);
}